// Round 5
// baseline (237.024 us; speedup 1.0000x reference)
//
#include <hip/hip_runtime.h>

#define BS 2
#define TS 128
#define DM 512
#define NH 8
#define DH 64
#define BN (BS*NH)            // 16

typedef __attribute__((ext_vector_type(8))) short short8;
typedef __attribute__((ext_vector_type(4))) float floatx4;

// ws layout (float element offsets). Total 5*SEG*4B = 2.62 MB.
#define SEG (BN*TS*DH)                  // 131072
#define OFS_Q    0                      // fp32 [bn][s][h] (+bias)
#define OFS_VA   SEG                    // fp32 [bn][s][h]
#define OFS_VB   (2*SEG)                // fp32 [bn][s][h]
#define OFS_K1B  (3*SEG)                // bf16 [bn][s][h] (+bias), SEG/2 floats
#define OFS_K2B  (3*SEG + SEG/2)        // bf16 [bn][s][h] (+bias)
#define OFS_Z    (4*SEG)                // fp32 z [b][q][n][h] = 256x512

__device__ __forceinline__ unsigned short f2bf(float x) {
  unsigned u = __float_as_uint(x);
  u += 0x7fff + ((u >> 16) & 1);        // round-to-nearest-even
  return (unsigned short)(u >> 16);
}
__device__ __forceinline__ float bf2f(short v) {
  return __uint_as_float(((unsigned)(unsigned short)v) << 16);
}

// ---------------------------------------------------------------------------
// Kernel A: 5 projections via bf16 MFMA (unchanged structure from R4; k1 now
// stored bf16). Block = (proj, n, rowtile of 64). 160 blocks.
// ---------------------------------------------------------------------------
__global__ __launch_bounds__(256) void proj_kernel(
    const float* __restrict__ x,   const float* __restrict__ Wk1,
    const float* __restrict__ Wk2, const float* __restrict__ Wq,
    const float* __restrict__ Wv12,const float* __restrict__ bk1,
    const float* __restrict__ bk2, const float* __restrict__ bq,
    float* __restrict__ ws)
{
  int t = blockIdx.x;
  int rt = t & 3; t >>= 2;
  int n  = t & 7; t >>= 3;
  int proj = t;                       // 0..4
  int tid = threadIdx.x;
  int wv = tid >> 6, ln = tid & 63, q4 = ln >> 4, l15 = ln & 15;

  const float* W;
  switch (proj) {
    case 0:  W = Wk1 + n*DM*DH;  break;
    case 1:  W = Wk2 + n*DM*DH;  break;
    case 2:  W = Wq  + n*DM*DH;  break;
    case 3:  W = Wv12 + n*2*DM*DH;  break;
    default: W = Wv12 + n*2*DM*DH + DM*DH;  break;
  }

  __shared__ __align__(16) short xb [64][520];
  __shared__ __align__(16) short wbt[64][520];

  for (int v = tid; v < 8192; v += 256) {
    int r = v >> 7, c = (v & 127) * 4;
    float4 xv = *(const float4*)&x[(size_t)(rt*64 + r)*DM + c];
    uint2 pk;
    pk.x = (unsigned)f2bf(xv.x) | ((unsigned)f2bf(xv.y) << 16);
    pk.y = (unsigned)f2bf(xv.z) | ((unsigned)f2bf(xv.w) << 16);
    *(uint2*)&xb[r][c] = pk;
  }
  {
    int nn = ln, kc8 = wv;
    for (int p = 0; p < 16; ++p) {
      int k0 = p*32 + kc8*8;
      unsigned short tmp[8];
      #pragma unroll
      for (int jj = 0; jj < 8; ++jj) tmp[jj] = f2bf(W[(k0 + jj)*DH + nn]);
      uint4 pk;
      pk.x = tmp[0] | ((unsigned)tmp[1] << 16);
      pk.y = tmp[2] | ((unsigned)tmp[3] << 16);
      pk.z = tmp[4] | ((unsigned)tmp[5] << 16);
      pk.w = tmp[6] | ((unsigned)tmp[7] << 16);
      *(uint4*)&wbt[nn][k0] = pk;
    }
  }
  __syncthreads();

  short8 afr[16];
  #pragma unroll
  for (int kc = 0; kc < 16; ++kc)
    afr[kc] = *(const short8*)&xb[wv*16 + l15][kc*32 + q4*8];

  floatx4 acc[4];
  #pragma unroll
  for (int nt = 0; nt < 4; ++nt) {
    floatx4 c = (floatx4){0.f,0.f,0.f,0.f};
    #pragma unroll
    for (int kc = 0; kc < 16; ++kc) {
      short8 bfr = *(const short8*)&wbt[nt*16 + l15][kc*32 + q4*8];
      c = __builtin_amdgcn_mfma_f32_16x16x32_bf16(afr[kc], bfr, c, 0,0,0);
    }
    acc[nt] = c;
  }

  #pragma unroll
  for (int nt = 0; nt < 4; ++nt) {
    int col = nt*16 + l15;
    float bias = 0.f;
    if (proj == 0) bias = bk1[n*DH + col];
    else if (proj == 1) bias = bk2[n*DH + col];
    else if (proj == 2) bias = bq[n*DH + col];
    #pragma unroll
    for (int r = 0; r < 4; ++r) {
      int row = rt*64 + wv*16 + q4*4 + r;
      int b = row >> 7, s = row & 127;
      size_t o = (size_t)((b*NH + n)*TS + s)*DH + col;
      float v = acc[nt][r] + bias;
      switch (proj) {
        case 0: ((unsigned short*)(ws + OFS_K1B))[o] = f2bf(v); break;
        case 1: ((unsigned short*)(ws + OFS_K2B))[o] = f2bf(v); break;
        case 2: ws[OFS_Q + o] = v; break;
        case 3: ws[OFS_VA + o] = v; break;
        default: ws[OFS_VB + o] = v; break;
      }
    }
  }
}

// ---------------------------------------------------------------------------
// Kernel B: per (bn,q), 2048 blocks (8 waves/SIMD TLP). S = k1 @ (k2 o qv)^T:
// A-frags = raw bf16 k1 straight from L2 (no build, no LDS); B rows built in
// LDS only for t < q. exp+mask in C-layout regs -> row/col marginals ->
// z = (R.va + C.vb)/D + b_V12.
// ---------------------------------------------------------------------------
__global__ __launch_bounds__(256) void attn_kernel(
    const float* __restrict__ ws, const float* __restrict__ bv12,
    float* __restrict__ z)
{
  int q  = blockIdx.x & 127;
  int bn = blockIdx.x >> 7;
  int tid = threadIdx.x;
  int wv = tid >> 6, ln = tid & 63, q4 = ln >> 4, l15 = ln & 15;
  int b = bn >> 3, n = bn & 7;
  float* zrow = z + ((size_t)(b*TS + q)*NH + n)*DH;

  if (q < 2) {                        // fully masked: sink takes all, vf(sink)=0
    if (tid < DH) zrow[tid] = 0.f;
    return;
  }

  const unsigned short* k1g = (const unsigned short*)(ws + OFS_K1B) + (size_t)bn*TS*DH;
  const unsigned short* k2g = (const unsigned short*)(ws + OFS_K2B) + (size_t)bn*TS*DH;
  const float* qg  = ws + OFS_Q  + ((size_t)bn*TS + q)*DH;
  const float* vag = ws + OFS_VA + (size_t)bn*TS*DH;
  const float* vbg = ws + OFS_VB + (size_t)bn*TS*DH;

  __shared__ __align__(16) short Bh[128][72];   // k2 o qv, bf16 (144B rows: 2-way banks = free)
  __shared__ float Rs[128];
  __shared__ float Cp[4][128];                  // per-wave col-marginal partials
  __shared__ float zpart[4][64];
  __shared__ float dpart[4];

  if (tid < 128) Rs[tid] = 0.f;
  ((float*)Cp)[tid] = 0.f; ((float*)Cp)[tid + 256] = 0.f;

  int T = (q + 15) >> 4;                        // active t-tiles (t < q)
  for (int i = tid; i < T*128; i += 256) {      // build Bh rows [0,16T)
    int r = i >> 3, c = (i & 7) * 8;
    short8 kv = *(const short8*)&k2g[r*DH + c];
    float4 q0 = *(const float4*)&qg[c];
    float4 q1 = *(const float4*)&qg[c + 4];
    unsigned short o8[8];
    o8[0] = f2bf(bf2f(kv[0]) * q0.x); o8[1] = f2bf(bf2f(kv[1]) * q0.y);
    o8[2] = f2bf(bf2f(kv[2]) * q0.z); o8[3] = f2bf(bf2f(kv[3]) * q0.w);
    o8[4] = f2bf(bf2f(kv[4]) * q1.x); o8[5] = f2bf(bf2f(kv[5]) * q1.y);
    o8[6] = f2bf(bf2f(kv[6]) * q1.z); o8[7] = f2bf(bf2f(kv[7]) * q1.w);
    uint4 pk;
    pk.x = o8[0] | ((unsigned)o8[1] << 16);
    pk.y = o8[2] | ((unsigned)o8[3] << 16);
    pk.z = o8[4] | ((unsigned)o8[5] << 16);
    pk.w = o8[6] | ((unsigned)o8[7] << 16);
    *(uint4*)&Bh[r][c] = pk;
  }

  short8 afr[2][2];                             // wave owns s-tiles si = wv, wv+4
  #pragma unroll
  for (int si2 = 0; si2 < 2; ++si2) {
    int m = (wv + 4*si2)*16 + l15;
    afr[si2][0] = *(const short8*)&k1g[m*DH + q4*8];
    afr[si2][1] = *(const short8*)&k1g[m*DH + q4*8 + 32];
  }
  __syncthreads();

  float rsum[2][4] = {{0.f,0.f,0.f,0.f},{0.f,0.f,0.f,0.f}};
  for (int tt = wv; tt < T; ++tt) {             // wave-uniform bounds
    int tg = tt*16 + l15;
    short8 b0 = *(const short8*)&Bh[tg][q4*8];
    short8 b1 = *(const short8*)&Bh[tg][q4*8 + 32];
    float csum = 0.f;
    #pragma unroll
    for (int si2 = 0; si2 < 2; ++si2) {
      int si = wv + 4*si2;
      if (si > tt || 16*si >= q - 1) continue;  // wave-uniform skip
      floatx4 c = (floatx4){0.f,0.f,0.f,0.f};
      c = __builtin_amdgcn_mfma_f32_16x16x32_bf16(afr[si2][0], b0, c, 0,0,0);
      c = __builtin_amdgcn_mfma_f32_16x16x32_bf16(afr[si2][1], b1, c, 0,0,0);
      #pragma unroll
      for (int rg = 0; rg < 4; ++rg) {          // C: row(s)=q4*4+rg, col(t)=l15
        int s = si*16 + q4*4 + rg;
        float e = (s < tg && tg < q) ? __expf(c[rg] * 0.015625f) : 0.f;
        rsum[si2][rg] += e;
        csum += e;
      }
    }
    csum += __shfl_xor(csum, 16, 64);           // reduce over q4 groups
    csum += __shfl_xor(csum, 32, 64);
    if (q4 == 0) Cp[wv][tg] = csum;
  }
  #pragma unroll
  for (int si2 = 0; si2 < 2; ++si2)
    #pragma unroll
    for (int rg = 0; rg < 4; ++rg) {            // row sums: reduce over l15 (t dir)
      float v = rsum[si2][rg];
      v += __shfl_xor(v, 1, 64); v += __shfl_xor(v, 2, 64);
      v += __shfl_xor(v, 4, 64); v += __shfl_xor(v, 8, 64);
      if (l15 == 0) Rs[(wv + 4*si2)*16 + q4*4 + rg] = v;
    }
  __syncthreads();

  int g = wv, h = ln;                           // z numerator + D partials
  float acc = 0.f, dp = 0.f;
  int imax = (q + 3) >> 2;                      // covers all s < q
  for (int i = 0; i < imax; ++i) {
    int s = g + 4*i;
    float rv = Rs[s];
    float cv = Cp[0][s] + Cp[1][s] + Cp[2][s] + Cp[3][s];
    acc = fmaf(rv, vag[s*DH + h], acc);
    acc = fmaf(cv, vbg[s*DH + h], acc);
    dp += rv;
  }
  zpart[g][h] = acc;
  if (ln == 0) dpart[g] = dp;
  __syncthreads();

  if (tid < 64) {
    float D = dpart[0] + dpart[1] + dpart[2] + dpart[3];
    float zv = (zpart[0][tid] + zpart[1][tid] + zpart[2][tid] + zpart[3][tid]) / D;
    zrow[tid] = zv + bv12[n*DH + tid];
  }
}

// ---------------------------------------------------------------------------
// Kernel C: out(256x512) = Z @ W_O + b_O (fp32). Block = 8 rows x 128 cols;
// thread does 4 rows per W load (4 fma/load). 128 blocks.
// ---------------------------------------------------------------------------
__global__ __launch_bounds__(256) void out_kernel(
    const float* __restrict__ zin, const float* __restrict__ Wo,
    const float* __restrict__ bo, float* __restrict__ out)
{
  int rt = blockIdx.x >> 2, cq = blockIdx.x & 3;
  int cl = threadIdx.x & 127, grp = threadIdx.x >> 7;
  int col = cq*128 + cl;

  __shared__ float zs[8][512];
  for (int v = threadIdx.x; v < 1024; v += 256) {
    int r = v >> 7, c = (v & 127) * 4;
    *(float4*)&zs[r][c] = *(const float4*)&zin[(size_t)(rt*8 + r)*512 + c];
  }
  __syncthreads();

  float acc[4] = {0.f, 0.f, 0.f, 0.f};
  #pragma unroll 8
  for (int k = 0; k < 512; ++k) {
    float w = Wo[k*512 + col];
    #pragma unroll
    for (int r = 0; r < 4; ++r)
      acc[r] = fmaf(zs[grp*4 + r][k], w, acc[r]);
  }
  float bv = bo[col];
  #pragma unroll
  for (int r = 0; r < 4; ++r)
    out[(size_t)(rt*8 + grp*4 + r)*512 + col] = acc[r] + bv;
}

extern "C" void kernel_launch(void* const* d_in, const int* in_sizes, int n_in,
                              void* d_out, int out_size, void* d_ws, size_t ws_size,
                              hipStream_t stream)
{
  const float* x    = (const float*)d_in[0];
  const float* Wk1  = (const float*)d_in[1];
  const float* Wk2  = (const float*)d_in[2];
  const float* Wq   = (const float*)d_in[3];
  const float* Wv12 = (const float*)d_in[4];
  const float* Wo   = (const float*)d_in[5];
  const float* bk1  = (const float*)d_in[6];
  const float* bk2  = (const float*)d_in[7];
  const float* bq   = (const float*)d_in[8];
  const float* bv12 = (const float*)d_in[9];
  const float* bo   = (const float*)d_in[10];
  float* out = (float*)d_out;
  float* ws  = (float*)d_ws;    // 2.62 MB

  proj_kernel<<<5*NH*4, 256, 0, stream>>>(x, Wk1, Wk2, Wq, Wv12, bk1, bk2, bq, ws);
  attn_kernel<<<BN*TS, 256, 0, stream>>>(ws, bv12, ws + OFS_Z);
  out_kernel<<<128, 256, 0, stream>>>(ws + OFS_Z, Wo, bo, out);
}

// Round 6
// 125.101 us; speedup vs baseline: 1.8947x; 1.8947x over previous
//
#include <hip/hip_runtime.h>

#define BS 2
#define TS 128
#define DM 512
#define NH 8
#define DH 64
#define BN (BS*NH)            // 16

typedef __attribute__((ext_vector_type(8))) short short8;
typedef __attribute__((ext_vector_type(4))) float floatx4;

// ws layout (float element offsets). Total 5*SEG*4B = 2.62 MB.
#define SEG (BN*TS*DH)                  // 131072
#define OFS_Q    0                      // fp32 [bn][s][h] (+bias)
#define OFS_VA   SEG                    // fp32 [bn][s][h]
#define OFS_VB   (2*SEG)                // fp32 [bn][s][h]
#define OFS_K1B  (3*SEG)                // bf16 [bn][s][h] (+bias), SEG/2 floats
#define OFS_K2B  (3*SEG + SEG/2)        // bf16 [bn][s][h] (+bias)
#define OFS_Z    (4*SEG)                // fp32 z [b][q][n][h] = 256x512

__device__ __forceinline__ unsigned short f2bf(float x) {
  unsigned u = __float_as_uint(x);
  u += 0x7fff + ((u >> 16) & 1);        // round-to-nearest-even
  return (unsigned short)(u >> 16);
}
__device__ __forceinline__ float bf2f(short v) {
  return __uint_as_float(((unsigned)(unsigned short)v) << 16);
}

// ---------------------------------------------------------------------------
// Kernel A: 5 projections via bf16 MFMA (unchanged from R5).
// Block = (proj, n, rowtile of 64). 160 blocks.
// ---------------------------------------------------------------------------
__global__ __launch_bounds__(256) void proj_kernel(
    const float* __restrict__ x,   const float* __restrict__ Wk1,
    const float* __restrict__ Wk2, const float* __restrict__ Wq,
    const float* __restrict__ Wv12,const float* __restrict__ bk1,
    const float* __restrict__ bk2, const float* __restrict__ bq,
    float* __restrict__ ws)
{
  int t = blockIdx.x;
  int rt = t & 3; t >>= 2;
  int n  = t & 7; t >>= 3;
  int proj = t;                       // 0..4
  int tid = threadIdx.x;
  int wv = tid >> 6, ln = tid & 63, q4 = ln >> 4, l15 = ln & 15;

  const float* W;
  switch (proj) {
    case 0:  W = Wk1 + n*DM*DH;  break;
    case 1:  W = Wk2 + n*DM*DH;  break;
    case 2:  W = Wq  + n*DM*DH;  break;
    case 3:  W = Wv12 + n*2*DM*DH;  break;
    default: W = Wv12 + n*2*DM*DH + DM*DH;  break;
  }

  __shared__ __align__(16) short xb [64][520];
  __shared__ __align__(16) short wbt[64][520];

  for (int v = tid; v < 8192; v += 256) {
    int r = v >> 7, c = (v & 127) * 4;
    float4 xv = *(const float4*)&x[(size_t)(rt*64 + r)*DM + c];
    uint2 pk;
    pk.x = (unsigned)f2bf(xv.x) | ((unsigned)f2bf(xv.y) << 16);
    pk.y = (unsigned)f2bf(xv.z) | ((unsigned)f2bf(xv.w) << 16);
    *(uint2*)&xb[r][c] = pk;
  }
  {
    int nn = ln, kc8 = wv;
    for (int p = 0; p < 16; ++p) {
      int k0 = p*32 + kc8*8;
      unsigned short tmp[8];
      #pragma unroll
      for (int jj = 0; jj < 8; ++jj) tmp[jj] = f2bf(W[(k0 + jj)*DH + nn]);
      uint4 pk;
      pk.x = tmp[0] | ((unsigned)tmp[1] << 16);
      pk.y = tmp[2] | ((unsigned)tmp[3] << 16);
      pk.z = tmp[4] | ((unsigned)tmp[5] << 16);
      pk.w = tmp[6] | ((unsigned)tmp[7] << 16);
      *(uint4*)&wbt[nn][k0] = pk;
    }
  }
  __syncthreads();

  short8 afr[16];
  #pragma unroll
  for (int kc = 0; kc < 16; ++kc)
    afr[kc] = *(const short8*)&xb[wv*16 + l15][kc*32 + q4*8];

  floatx4 acc[4];
  #pragma unroll
  for (int nt = 0; nt < 4; ++nt) {
    floatx4 c = (floatx4){0.f,0.f,0.f,0.f};
    #pragma unroll
    for (int kc = 0; kc < 16; ++kc) {
      short8 bfr = *(const short8*)&wbt[nt*16 + l15][kc*32 + q4*8];
      c = __builtin_amdgcn_mfma_f32_16x16x32_bf16(afr[kc], bfr, c, 0,0,0);
    }
    acc[nt] = c;
  }

  #pragma unroll
  for (int nt = 0; nt < 4; ++nt) {
    int col = nt*16 + l15;
    float bias = 0.f;
    if (proj == 0) bias = bk1[n*DH + col];
    else if (proj == 1) bias = bk2[n*DH + col];
    else if (proj == 2) bias = bq[n*DH + col];
    #pragma unroll
    for (int r = 0; r < 4; ++r) {
      int row = rt*64 + wv*16 + q4*4 + r;
      int b = row >> 7, s = row & 127;
      size_t o = (size_t)((b*NH + n)*TS + s)*DH + col;
      float v = acc[nt][r] + bias;
      switch (proj) {
        case 0: ((unsigned short*)(ws + OFS_K1B))[o] = f2bf(v); break;
        case 1: ((unsigned short*)(ws + OFS_K2B))[o] = f2bf(v); break;
        case 2: ws[OFS_Q + o] = v; break;
        case 3: ws[OFS_VA + o] = v; break;
        default: ws[OFS_VB + o] = v; break;
      }
    }
  }
}

// ---------------------------------------------------------------------------
// Kernel B: per (bn,q), 2048 blocks (unchanged from R5). S = k1 @ (k2 o qv)^T,
// A-frags straight from bf16 k1 in L2; B rows built in LDS for t < q only.
// ---------------------------------------------------------------------------
__global__ __launch_bounds__(256) void attn_kernel(
    const float* __restrict__ ws, const float* __restrict__ bv12,
    float* __restrict__ z)
{
  int q  = blockIdx.x & 127;
  int bn = blockIdx.x >> 7;
  int tid = threadIdx.x;
  int wv = tid >> 6, ln = tid & 63, q4 = ln >> 4, l15 = ln & 15;
  int b = bn >> 3, n = bn & 7;
  float* zrow = z + ((size_t)(b*TS + q)*NH + n)*DH;

  if (q < 2) {                        // fully masked: sink takes all, vf(sink)=0
    if (tid < DH) zrow[tid] = 0.f;
    return;
  }

  const unsigned short* k1g = (const unsigned short*)(ws + OFS_K1B) + (size_t)bn*TS*DH;
  const unsigned short* k2g = (const unsigned short*)(ws + OFS_K2B) + (size_t)bn*TS*DH;
  const float* qg  = ws + OFS_Q  + ((size_t)bn*TS + q)*DH;
  const float* vag = ws + OFS_VA + (size_t)bn*TS*DH;
  const float* vbg = ws + OFS_VB + (size_t)bn*TS*DH;

  __shared__ __align__(16) short Bh[128][72];
  __shared__ float Rs[128];
  __shared__ float Cp[4][128];
  __shared__ float zpart[4][64];
  __shared__ float dpart[4];

  if (tid < 128) Rs[tid] = 0.f;
  ((float*)Cp)[tid] = 0.f; ((float*)Cp)[tid + 256] = 0.f;

  int T = (q + 15) >> 4;                        // active t-tiles (t < q)
  for (int i = tid; i < T*128; i += 256) {
    int r = i >> 3, c = (i & 7) * 8;
    short8 kv = *(const short8*)&k2g[r*DH + c];
    float4 q0 = *(const float4*)&qg[c];
    float4 q1 = *(const float4*)&qg[c + 4];
    unsigned short o8[8];
    o8[0] = f2bf(bf2f(kv[0]) * q0.x); o8[1] = f2bf(bf2f(kv[1]) * q0.y);
    o8[2] = f2bf(bf2f(kv[2]) * q0.z); o8[3] = f2bf(bf2f(kv[3]) * q0.w);
    o8[4] = f2bf(bf2f(kv[4]) * q1.x); o8[5] = f2bf(bf2f(kv[5]) * q1.y);
    o8[6] = f2bf(bf2f(kv[6]) * q1.z); o8[7] = f2bf(bf2f(kv[7]) * q1.w);
    uint4 pk;
    pk.x = o8[0] | ((unsigned)o8[1] << 16);
    pk.y = o8[2] | ((unsigned)o8[3] << 16);
    pk.z = o8[4] | ((unsigned)o8[5] << 16);
    pk.w = o8[6] | ((unsigned)o8[7] << 16);
    *(uint4*)&Bh[r][c] = pk;
  }

  short8 afr[2][2];                             // wave owns s-tiles si = wv, wv+4
  #pragma unroll
  for (int si2 = 0; si2 < 2; ++si2) {
    int m = (wv + 4*si2)*16 + l15;
    afr[si2][0] = *(const short8*)&k1g[m*DH + q4*8];
    afr[si2][1] = *(const short8*)&k1g[m*DH + q4*8 + 32];
  }
  __syncthreads();

  float rsum[2][4] = {{0.f,0.f,0.f,0.f},{0.f,0.f,0.f,0.f}};
  for (int tt = wv; tt < T; ++tt) {
    int tg = tt*16 + l15;
    short8 b0 = *(const short8*)&Bh[tg][q4*8];
    short8 b1 = *(const short8*)&Bh[tg][q4*8 + 32];
    float csum = 0.f;
    #pragma unroll
    for (int si2 = 0; si2 < 2; ++si2) {
      int si = wv + 4*si2;
      if (si > tt || 16*si >= q - 1) continue;
      floatx4 c = (floatx4){0.f,0.f,0.f,0.f};
      c = __builtin_amdgcn_mfma_f32_16x16x32_bf16(afr[si2][0], b0, c, 0,0,0);
      c = __builtin_amdgcn_mfma_f32_16x16x32_bf16(afr[si2][1], b1, c, 0,0,0);
      #pragma unroll
      for (int rg = 0; rg < 4; ++rg) {
        int s = si*16 + q4*4 + rg;
        float e = (s < tg && tg < q) ? __expf(c[rg] * 0.015625f) : 0.f;
        rsum[si2][rg] += e;
        csum += e;
      }
    }
    csum += __shfl_xor(csum, 16, 64);
    csum += __shfl_xor(csum, 32, 64);
    if (q4 == 0) Cp[wv][tg] = csum;
  }
  #pragma unroll
  for (int si2 = 0; si2 < 2; ++si2)
    #pragma unroll
    for (int rg = 0; rg < 4; ++rg) {
      float v = rsum[si2][rg];
      v += __shfl_xor(v, 1, 64); v += __shfl_xor(v, 2, 64);
      v += __shfl_xor(v, 4, 64); v += __shfl_xor(v, 8, 64);
      if (l15 == 0) Rs[(wv + 4*si2)*16 + q4*4 + rg] = v;
    }
  __syncthreads();

  int g = wv, h = ln;
  float acc = 0.f, dp = 0.f;
  int imax = (q + 3) >> 2;
  for (int i = 0; i < imax; ++i) {
    int s = g + 4*i;
    float rv = Rs[s];
    float cv = Cp[0][s] + Cp[1][s] + Cp[2][s] + Cp[3][s];
    acc = fmaf(rv, vag[s*DH + h], acc);
    acc = fmaf(cv, vbg[s*DH + h], acc);
    dp += rv;
  }
  zpart[g][h] = acc;
  if (ln == 0) dpart[g] = dp;
  __syncthreads();

  if (tid < 64) {
    float D = dpart[0] + dpart[1] + dpart[2] + dpart[3];
    float zv = (zpart[0][tid] + zpart[1][tid] + zpart[2][tid] + zpart[3][tid]) / D;
    zrow[tid] = zv + bv12[n*DH + tid];
  }
}

// ---------------------------------------------------------------------------
// Kernel C: out(256x512) = Z @ W_O + b_O via bf16 MFMA — proj_kernel's proven
// structure. Block = (rowtile of 64) x (coltile of 64) = 32 blocks; Z-tile +
// transposed Wo-tile staged bf16 in LDS once; 64 MFMA/wave, no latency chain.
// ---------------------------------------------------------------------------
__global__ __launch_bounds__(256) void out_kernel(
    const float* __restrict__ zin, const float* __restrict__ Wo,
    const float* __restrict__ bo, float* __restrict__ out)
{
  int rt = blockIdx.x >> 3;           // 0..3: rows rt*64..+64
  int ct = blockIdx.x & 7;            // 0..7: cols ct*64..+64
  int tid = threadIdx.x;
  int wv = tid >> 6, ln = tid & 63, q4 = ln >> 4, l15 = ln & 15;

  __shared__ __align__(16) short zb [64][520];   // Z rows, bf16
  __shared__ __align__(16) short wbt[64][520];   // Wo^T [col][k], bf16

  for (int v = tid; v < 8192; v += 256) {        // stage Z: 64x512 via float4
    int r = v >> 7, c = (v & 127) * 4;
    float4 zv = *(const float4*)&zin[(size_t)(rt*64 + r)*DM + c];
    uint2 pk;
    pk.x = (unsigned)f2bf(zv.x) | ((unsigned)f2bf(zv.y) << 16);
    pk.y = (unsigned)f2bf(zv.z) | ((unsigned)f2bf(zv.w) << 16);
    *(uint2*)&zb[r][c] = pk;
  }
  {                                              // stage Wo^T (coalesced across ln)
    int nn = ln, kc8 = wv;
    for (int p = 0; p < 16; ++p) {
      int k0 = p*32 + kc8*8;
      unsigned short tmp[8];
      #pragma unroll
      for (int jj = 0; jj < 8; ++jj)
        tmp[jj] = f2bf(Wo[(size_t)(k0 + jj)*DM + ct*64 + nn]);
      uint4 pk;
      pk.x = tmp[0] | ((unsigned)tmp[1] << 16);
      pk.y = tmp[2] | ((unsigned)tmp[3] << 16);
      pk.z = tmp[4] | ((unsigned)tmp[5] << 16);
      pk.w = tmp[6] | ((unsigned)tmp[7] << 16);
      *(uint4*)&wbt[nn][k0] = pk;
    }
  }
  __syncthreads();

  short8 afr[16];
  #pragma unroll
  for (int kc = 0; kc < 16; ++kc)
    afr[kc] = *(const short8*)&zb[wv*16 + l15][kc*32 + q4*8];

  floatx4 acc[4];
  #pragma unroll
  for (int nt = 0; nt < 4; ++nt) {
    floatx4 c = (floatx4){0.f,0.f,0.f,0.f};
    #pragma unroll
    for (int kc = 0; kc < 16; ++kc) {
      short8 bfr = *(const short8*)&wbt[nt*16 + l15][kc*32 + q4*8];
      c = __builtin_amdgcn_mfma_f32_16x16x32_bf16(afr[kc], bfr, c, 0,0,0);
    }
    acc[nt] = c;
  }

  #pragma unroll
  for (int nt = 0; nt < 4; ++nt) {
    int col = ct*64 + nt*16 + l15;
    float bias = bo[col];
    #pragma unroll
    for (int r = 0; r < 4; ++r) {
      int row = rt*64 + wv*16 + q4*4 + r;        // C layout: row=(l>>4)*4+reg
      out[(size_t)row*DM + col] = acc[nt][r] + bias;
    }
  }
}

extern "C" void kernel_launch(void* const* d_in, const int* in_sizes, int n_in,
                              void* d_out, int out_size, void* d_ws, size_t ws_size,
                              hipStream_t stream)
{
  const float* x    = (const float*)d_in[0];
  const float* Wk1  = (const float*)d_in[1];
  const float* Wk2  = (const float*)d_in[2];
  const float* Wq   = (const float*)d_in[3];
  const float* Wv12 = (const float*)d_in[4];
  const float* Wo   = (const float*)d_in[5];
  const float* bk1  = (const float*)d_in[6];
  const float* bk2  = (const float*)d_in[7];
  const float* bq   = (const float*)d_in[8];
  const float* bv12 = (const float*)d_in[9];
  const float* bo   = (const float*)d_in[10];
  float* out = (float*)d_out;
  float* ws  = (float*)d_ws;    // 2.62 MB

  proj_kernel<<<5*NH*4, 256, 0, stream>>>(x, Wk1, Wk2, Wq, Wv12, bk1, bk2, bq, ws);
  attn_kernel<<<BN*TS, 256, 0, stream>>>(ws, bv12, ws + OFS_Z);
  out_kernel<<<32, 256, 0, stream>>>(ws + OFS_Z, Wo, bo, out);
}

// Round 7
// 116.155 us; speedup vs baseline: 2.0406x; 1.0770x over previous
//
#include <hip/hip_runtime.h>

#define BS 2
#define TS 128
#define DM 512
#define NH 8
#define DH 64
#define BN (BS*NH)            // 16

typedef __attribute__((ext_vector_type(8))) short short8;
typedef __attribute__((ext_vector_type(4))) float floatx4;

// ws layout (float element offsets). Total 4*SEG*4B = 2.1 MB.
#define SEG (BN*TS*DH)                  // 131072
#define OFS_Q    0                      // fp32 [bn][s][h] (+bias)
#define OFS_VA   SEG                    // fp32 [bn][s][h]
#define OFS_VB   (2*SEG)                // fp32 [bn][s][h]
#define OFS_K1B  (3*SEG)                // bf16 [bn][s][h] (+bias), SEG/2 floats
#define OFS_K2B  (3*SEG + SEG/2)        // bf16 [bn][s][h] (+bias)

__device__ __forceinline__ unsigned short f2bf(float x) {
  unsigned u = __float_as_uint(x);
  u += 0x7fff + ((u >> 16) & 1);        // round-to-nearest-even
  return (unsigned short)(u >> 16);
}
__device__ __forceinline__ float bf2f(short v) {
  return __uint_as_float(((unsigned)(unsigned short)v) << 16);
}

// ---------------------------------------------------------------------------
// Kernel A: 5 projections via bf16 MFMA (R5 structure) + d_out := b_O init
// (so attn can atomicAdd onto bias; harness re-poisons d_out to 0xAA).
// Block = (proj, n, rowtile of 64). 160 blocks.
// ---------------------------------------------------------------------------
__global__ __launch_bounds__(256) void proj_kernel(
    const float* __restrict__ x,   const float* __restrict__ Wk1,
    const float* __restrict__ Wk2, const float* __restrict__ Wq,
    const float* __restrict__ Wv12,const float* __restrict__ bk1,
    const float* __restrict__ bk2, const float* __restrict__ bq,
    const float* __restrict__ bo,  float* __restrict__ out,
    float* __restrict__ ws)
{
  int t = blockIdx.x;
  int rt = t & 3; t >>= 2;
  int n  = t & 7; t >>= 3;
  int proj = t;                       // 0..4
  int tid = threadIdx.x;
  int wv = tid >> 6, ln = tid & 63, q4 = ln >> 4, l15 = ln & 15;

  // init out = bias (grid-stride over 256x512)
  for (int i = blockIdx.x*256 + tid; i < BS*TS*DM; i += 160*256)
    out[i] = bo[i & (DM-1)];

  const float* W;
  switch (proj) {
    case 0:  W = Wk1 + n*DM*DH;  break;
    case 1:  W = Wk2 + n*DM*DH;  break;
    case 2:  W = Wq  + n*DM*DH;  break;
    case 3:  W = Wv12 + n*2*DM*DH;  break;
    default: W = Wv12 + n*2*DM*DH + DM*DH;  break;
  }

  __shared__ __align__(16) short xb [64][520];
  __shared__ __align__(16) short wbt[64][520];

  for (int v = tid; v < 8192; v += 256) {
    int r = v >> 7, c = (v & 127) * 4;
    float4 xv = *(const float4*)&x[(size_t)(rt*64 + r)*DM + c];
    uint2 pk;
    pk.x = (unsigned)f2bf(xv.x) | ((unsigned)f2bf(xv.y) << 16);
    pk.y = (unsigned)f2bf(xv.z) | ((unsigned)f2bf(xv.w) << 16);
    *(uint2*)&xb[r][c] = pk;
  }
  {
    int nn = ln, kc8 = wv;
    for (int p = 0; p < 16; ++p) {
      int k0 = p*32 + kc8*8;
      unsigned short tmp[8];
      #pragma unroll
      for (int jj = 0; jj < 8; ++jj) tmp[jj] = f2bf(W[(k0 + jj)*DH + nn]);
      uint4 pk;
      pk.x = tmp[0] | ((unsigned)tmp[1] << 16);
      pk.y = tmp[2] | ((unsigned)tmp[3] << 16);
      pk.z = tmp[4] | ((unsigned)tmp[5] << 16);
      pk.w = tmp[6] | ((unsigned)tmp[7] << 16);
      *(uint4*)&wbt[nn][k0] = pk;
    }
  }
  __syncthreads();

  short8 afr[16];
  #pragma unroll
  for (int kc = 0; kc < 16; ++kc)
    afr[kc] = *(const short8*)&xb[wv*16 + l15][kc*32 + q4*8];

  floatx4 acc[4];
  #pragma unroll
  for (int nt = 0; nt < 4; ++nt) {
    floatx4 c = (floatx4){0.f,0.f,0.f,0.f};
    #pragma unroll
    for (int kc = 0; kc < 16; ++kc) {
      short8 bfr = *(const short8*)&wbt[nt*16 + l15][kc*32 + q4*8];
      c = __builtin_amdgcn_mfma_f32_16x16x32_bf16(afr[kc], bfr, c, 0,0,0);
    }
    acc[nt] = c;
  }

  #pragma unroll
  for (int nt = 0; nt < 4; ++nt) {
    int col = nt*16 + l15;
    float bias = 0.f;
    if (proj == 0) bias = bk1[n*DH + col];
    else if (proj == 1) bias = bk2[n*DH + col];
    else if (proj == 2) bias = bq[n*DH + col];
    #pragma unroll
    for (int r = 0; r < 4; ++r) {
      int row = rt*64 + wv*16 + q4*4 + r;
      int b = row >> 7, s = row & 127;
      size_t o = (size_t)((b*NH + n)*TS + s)*DH + col;
      float v = acc[nt][r] + bias;
      switch (proj) {
        case 0: ((unsigned short*)(ws + OFS_K1B))[o] = f2bf(v); break;
        case 1: ((unsigned short*)(ws + OFS_K2B))[o] = f2bf(v); break;
        case 2: ws[OFS_Q + o] = v; break;
        case 3: ws[OFS_VA + o] = v; break;
        default: ws[OFS_VB + o] = v; break;
      }
    }
  }
}

// ---------------------------------------------------------------------------
// Kernel B: per (bn,q), 2048 blocks. S = k1 @ (k2 o qv)^T (MFMA, A-frags from
// bf16 k1 in L2), exp+mask -> row/col marginals -> z = (R.va + C.vb)/D + bv12
// -> FUSED epilogue: out[row,:] += z @ Wo[n] via fp32 atomics (bias pre-set).
// ---------------------------------------------------------------------------
__global__ __launch_bounds__(256) void attn_kernel(
    const float* __restrict__ ws, const float* __restrict__ bv12,
    const float* __restrict__ Wo, float* __restrict__ out)
{
  int q  = blockIdx.x & 127;
  int bn = blockIdx.x >> 7;
  int tid = threadIdx.x;
  int wv = tid >> 6, ln = tid & 63, q4 = ln >> 4, l15 = ln & 15;
  int b = bn >> 3, n = bn & 7;

  if (q < 2) return;                  // z=0 -> contributes nothing beyond bias

  const unsigned short* k1g = (const unsigned short*)(ws + OFS_K1B) + (size_t)bn*TS*DH;
  const unsigned short* k2g = (const unsigned short*)(ws + OFS_K2B) + (size_t)bn*TS*DH;
  const float* qg  = ws + OFS_Q  + ((size_t)bn*TS + q)*DH;
  const float* vag = ws + OFS_VA + (size_t)bn*TS*DH;
  const float* vbg = ws + OFS_VB + (size_t)bn*TS*DH;

  __shared__ __align__(16) short Bh[128][72];   // k2 o qv, bf16 (2-way banks = free)
  __shared__ float Rs[128];
  __shared__ float Cp[4][128];                  // per-wave col-marginal partials
  __shared__ float Cs[128];                     // combined col marginals
  __shared__ float zpart[4][64];
  __shared__ float dpart[4];
  __shared__ float zs[64];                      // final z row

  ((float*)Cp)[tid] = 0.f; ((float*)Cp)[tid + 256] = 0.f;

  int T = (q + 15) >> 4;                        // active t-tiles (t < q)
  for (int i = tid; i < T*128; i += 256) {      // build Bh rows [0,16T)
    int r = i >> 3, c = (i & 7) * 8;
    short8 kv = *(const short8*)&k2g[r*DH + c];
    float4 q0 = *(const float4*)&qg[c];
    float4 q1 = *(const float4*)&qg[c + 4];
    unsigned short o8[8];
    o8[0] = f2bf(bf2f(kv[0]) * q0.x); o8[1] = f2bf(bf2f(kv[1]) * q0.y);
    o8[2] = f2bf(bf2f(kv[2]) * q0.z); o8[3] = f2bf(bf2f(kv[3]) * q0.w);
    o8[4] = f2bf(bf2f(kv[4]) * q1.x); o8[5] = f2bf(bf2f(kv[5]) * q1.y);
    o8[6] = f2bf(bf2f(kv[6]) * q1.z); o8[7] = f2bf(bf2f(kv[7]) * q1.w);
    uint4 pk;
    pk.x = o8[0] | ((unsigned)o8[1] << 16);
    pk.y = o8[2] | ((unsigned)o8[3] << 16);
    pk.z = o8[4] | ((unsigned)o8[5] << 16);
    pk.w = o8[6] | ((unsigned)o8[7] << 16);
    *(uint4*)&Bh[r][c] = pk;
  }

  short8 afr[2][2];                             // wave owns s-tiles si = wv, wv+4
  #pragma unroll
  for (int si2 = 0; si2 < 2; ++si2) {
    int m = (wv + 4*si2)*16 + l15;
    afr[si2][0] = *(const short8*)&k1g[m*DH + q4*8];
    afr[si2][1] = *(const short8*)&k1g[m*DH + q4*8 + 32];
  }
  __syncthreads();

  float rsum[2][4] = {{0.f,0.f,0.f,0.f},{0.f,0.f,0.f,0.f}};
  for (int tt = wv; tt < T; ++tt) {             // wave-uniform bounds
    int tg = tt*16 + l15;
    short8 b0 = *(const short8*)&Bh[tg][q4*8];
    short8 b1 = *(const short8*)&Bh[tg][q4*8 + 32];
    float csum = 0.f;
    #pragma unroll
    for (int si2 = 0; si2 < 2; ++si2) {
      int si = wv + 4*si2;
      if (si > tt || 16*si >= q - 1) continue;  // wave-uniform skip
      floatx4 c = (floatx4){0.f,0.f,0.f,0.f};
      c = __builtin_amdgcn_mfma_f32_16x16x32_bf16(afr[si2][0], b0, c, 0,0,0);
      c = __builtin_amdgcn_mfma_f32_16x16x32_bf16(afr[si2][1], b1, c, 0,0,0);
      #pragma unroll
      for (int rg = 0; rg < 4; ++rg) {          // C: row(s)=q4*4+rg, col(t)=l15
        int s = si*16 + q4*4 + rg;
        float e = (s < tg && tg < q) ? __expf(c[rg] * 0.015625f) : 0.f;
        rsum[si2][rg] += e;
        csum += e;
      }
    }
    csum += __shfl_xor(csum, 16, 64);           // reduce over q4 groups
    csum += __shfl_xor(csum, 32, 64);
    if (q4 == 0) Cp[wv][tg] = csum;
  }
  #pragma unroll
  for (int si2 = 0; si2 < 2; ++si2)
    #pragma unroll
    for (int rg = 0; rg < 4; ++rg) {            // row sums: reduce over l15
      float v = rsum[si2][rg];
      v += __shfl_xor(v, 1, 64); v += __shfl_xor(v, 2, 64);
      v += __shfl_xor(v, 4, 64); v += __shfl_xor(v, 8, 64);
      if (l15 == 0) Rs[(wv + 4*si2)*16 + q4*4 + rg] = v;
    }
  __syncthreads();

  if (tid < 128) Cs[tid] = Cp[0][tid] + Cp[1][tid] + Cp[2][tid] + Cp[3][tid];
  __syncthreads();

  int g = wv, h = ln;                           // z numerator + D partials
  float acc = 0.f, dp = 0.f;
  int imax = (q + 3) >> 2;
  for (int i = 0; i < imax; ++i) {
    int s = g + 4*i;
    float rv = Rs[s], cv = Cs[s];
    acc = fmaf(rv, vag[s*DH + h], acc);
    acc = fmaf(cv, vbg[s*DH + h], acc);
    dp += rv;
  }
  zpart[g][h] = acc;
  if (ln == 0) dpart[g] = dp;
  __syncthreads();

  if (tid < 64) {
    float D = dpart[0] + dpart[1] + dpart[2] + dpart[3];
    zs[tid] = (zpart[0][tid] + zpart[1][tid] + zpart[2][tid] + zpart[3][tid]) / D
              + bv12[n*DH + tid];
  }
  __syncthreads();

  // fused out: out[row, :] += zs @ Wo[n]  (fp32, Wo slice L2-resident)
  const float* WoN = Wo + (size_t)n*DH*DM;
  float* orow = out + (size_t)(b*TS + q)*DM;
  float a0 = 0.f, a1 = 0.f;
  #pragma unroll 8
  for (int h2 = 0; h2 < DH; ++h2) {
    float zv = zs[h2];
    a0 = fmaf(zv, WoN[h2*DM + tid],       a0);
    a1 = fmaf(zv, WoN[h2*DM + tid + 256], a1);
  }
  atomicAdd(&orow[tid],       a0);
  atomicAdd(&orow[tid + 256], a1);
}

extern "C" void kernel_launch(void* const* d_in, const int* in_sizes, int n_in,
                              void* d_out, int out_size, void* d_ws, size_t ws_size,
                              hipStream_t stream)
{
  const float* x    = (const float*)d_in[0];
  const float* Wk1  = (const float*)d_in[1];
  const float* Wk2  = (const float*)d_in[2];
  const float* Wq   = (const float*)d_in[3];
  const float* Wv12 = (const float*)d_in[4];
  const float* Wo   = (const float*)d_in[5];
  const float* bk1  = (const float*)d_in[6];
  const float* bk2  = (const float*)d_in[7];
  const float* bq   = (const float*)d_in[8];
  const float* bv12 = (const float*)d_in[9];
  const float* bo   = (const float*)d_in[10];
  float* out = (float*)d_out;
  float* ws  = (float*)d_ws;    // 2.1 MB

  proj_kernel<<<5*NH*4, 256, 0, stream>>>(x, Wk1, Wk2, Wq, Wv12,
                                          bk1, bk2, bq, bo, out, ws);
  attn_kernel<<<BN*TS, 256, 0, stream>>>(ws, bv12, Wo, out);
}